// Round 2
// baseline (4111.151 us; speedup 1.0000x reference)
//
#include <hip/hip_runtime.h>

typedef unsigned short u16;
typedef __bf16 bf16x8 __attribute__((ext_vector_type(8)));
typedef float f32x4 __attribute__((ext_vector_type(4)));

#define T_STEPS 8
#define KT_COUNT 144        // K=4608 per half, BK=32

__device__ __forceinline__ u16 f2bf(float f) {
    unsigned u = __float_as_uint(f);
    return (u16)((u + 0x7fff + ((u >> 16) & 1)) >> 16);
}
__device__ __forceinline__ float sigmoidf(float x) {
    return 1.f / (1.f + expf(-x));
}

// ---------------------------------------------------------------------------
// Repack conv_w (fp32) [2048][1024][3][3] into bf16 x-part / h-part GEMM
// layouts: [co_blk(16)][kt(144)][quad(4)][co_in(128)][j(8)], k' = r*512 + ci.
// ---------------------------------------------------------------------------
__global__ void repack_w(const float* __restrict__ w,
                         u16* __restrict__ wx, u16* __restrict__ wh) {
    int g = blockIdx.x * 256 + threadIdx.x;   // 2*16*144*4*128 = 2,359,296
    int co_in = g & 127; g >>= 7;
    int quad  = g & 3;   g >>= 2;
    int kt    = g % 144; g /= 144;
    int co_blk = g & 15; g >>= 4;
    int part = g;                              // 0 = x, 1 = h
    int co = co_blk * 128 + co_in;
    int k0 = kt * 32 + quad * 8;
    int r  = k0 >> 9;          // tap index 0..8
    int ci = k0 & 511;
    const float* src = w + ((size_t)co * 1024 + (size_t)part * 512 + ci) * 9 + r;
    u16* dst = (part ? wh : wx) +
               ((((size_t)co_blk * 144 + kt) * 4 + quad) * 128 + co_in) * 8;
    union { u16 u[8]; uint4 v; } tmp;
#pragma unroll
    for (int j = 0; j < 8; j++) tmp.u[j] = f2bf(src[(size_t)j * 9]);
    *(uint4*)dst = tmp.v;
}

// ---------------------------------------------------------------------------
// Implicit-im2col conv GEMM with boundary predication (no padded buffer).
// Activations layout [b][c(512)][T(8)][32][32]; element fp32 (F32) or bf16.
// XMODE: N covers 2 timesteps x 2 batch (plane = n>>10, t = t0 + plane>>1,
//        b = plane&1).  !XMODE (h-conv): N=2048, b = n>>10, t = t0.
// 128x128 tile, BK=32, 512 threads = 8 waves (4m x 2n), 16x16x32 bf16 MFMA.
// ---------------------------------------------------------------------------
template<bool XMODE, bool F32>
__global__ __launch_bounds__(512) void conv_gemm(
    const u16* __restrict__ Wp, const void* __restrict__ Bsrc, int t0,
    float* __restrict__ Z, int ldz) {
    __shared__ __align__(16) u16 As[4][128][8];   // [quad][co_in][j]  8KB
    __shared__ __align__(16) u16 Bs[4][128][8];   // [quad][n][j]      8KB

    const int tid = threadIdx.x;
    const int co_blk = blockIdx.y;
    const int n0 = blockIdx.x * 128;
    const int wave = tid >> 6, lane = tid & 63;
    const int wm = wave >> 1, wn = wave & 1;      // 4 x 2 wave grid
    const int q_l = lane >> 4, m_l = lane & 15;

    // B staging coords: thread -> (quad sq, column sn)
    const int sq = tid >> 7;
    const int sn = tid & 127;
    const int n_g = n0 + sn;
    int bb_, tt;
    if (XMODE) { int plane = n_g >> 10; bb_ = plane & 1; tt = t0 + (plane >> 1); }
    else       { bb_ = n_g >> 10; tt = t0; }
    const int s = n_g & 1023;
    const int py = s >> 5, px = s & 31;
    const size_t nbase = ((size_t)bb_ * 512 * T_STEPS + tt) * 1024;

    const uint4* Ag = (const uint4*)(Wp + (size_t)co_blk * KT_COUNT * 4096);

    f32x4 acc[2][4];
#pragma unroll
    for (int i = 0; i < 2; i++)
#pragma unroll
        for (int j = 0; j < 4; j++) acc[i][j] = (f32x4){0.f, 0.f, 0.f, 0.f};

    for (int kt = 0; kt < KT_COUNT; ++kt) {
        const int r = kt >> 4;                 // tap 0..8 (16 k-tiles per tap)
        const int ci0 = (kt & 15) * 32;
        const int y2 = py + r / 3 - 1;
        const int x2 = px + r % 3 - 1;
        const bool ok = ((unsigned)y2 < 32u) && ((unsigned)x2 < 32u);

        uint4 a_reg = Ag[(size_t)kt * 512 + tid];

        union { u16 u[8]; uint4 v; } bb;
        const size_t e0 = nbase + (size_t)(ci0 + sq * 8) * (T_STEPS * 1024)
                        + (size_t)y2 * 32 + x2;
        if (ok) {
            if (F32) {
                const float* bs = (const float*)Bsrc;
#pragma unroll
                for (int j = 0; j < 8; j++)
                    bb.u[j] = f2bf(bs[e0 + (size_t)j * (T_STEPS * 1024)]);
            } else {
                const u16* bs = (const u16*)Bsrc;
#pragma unroll
                for (int j = 0; j < 8; j++)
                    bb.u[j] = bs[e0 + (size_t)j * (T_STEPS * 1024)];
            }
        } else {
            bb.v = (uint4){0, 0, 0, 0};
        }

        __syncthreads();   // previous iter's LDS reads complete
        ((uint4*)&As[0][0][0])[tid] = a_reg;
        ((uint4*)&Bs[0][0][0])[tid] = bb.v;
        __syncthreads();   // LDS writes visible

        bf16x8 af[2], bfr[4];
#pragma unroll
        for (int mt = 0; mt < 2; mt++)
            af[mt] = *(const bf16x8*)&As[q_l][wm * 32 + mt * 16 + m_l][0];
#pragma unroll
        for (int nt = 0; nt < 4; nt++)
            bfr[nt] = *(const bf16x8*)&Bs[q_l][wn * 64 + nt * 16 + m_l][0];
#pragma unroll
        for (int mt = 0; mt < 2; mt++)
#pragma unroll
            for (int nt = 0; nt < 4; nt++)
                acc[mt][nt] = __builtin_amdgcn_mfma_f32_16x16x32_bf16(
                    af[mt], bfr[nt], acc[mt][nt], 0, 0, 0);
    }

    // Epilogue: C/D layout col=lane&15 (n), row=(lane>>4)*4+reg (m)
#pragma unroll
    for (int mt = 0; mt < 2; mt++)
#pragma unroll
        for (int nt = 0; nt < 4; nt++)
#pragma unroll
            for (int reg = 0; reg < 4; reg++) {
                int co = co_blk * 128 + wm * 32 + mt * 16 + q_l * 4 + reg;
                int n  = n0 + wn * 64 + nt * 16 + m_l;
                Z[(size_t)co * ldz + n] = acc[mt][nt][reg];
            }
}

// ---------------------------------------------------------------------------
// Gates: fp32 math. zx rows ld 4096 (2-t chunk), zh rows ld 2048.
// is_first: H_{-1}=C_{-1}=0 -> skip zh and C reads entirely.
// ---------------------------------------------------------------------------
__global__ void gates_kernel(
    const float* __restrict__ zx, int nxoff,
    const float* __restrict__ zh,
    const float* __restrict__ bias,
    const float* __restrict__ wci, const float* __restrict__ wcf,
    const float* __restrict__ wco,
    float* __restrict__ C, int is_first,
    u16* __restrict__ Y, int t,
    float* __restrict__ outp) {
    int g = blockIdx.x * 256 + threadIdx.x;    // 0 .. 2*512*1024-1
    int s = g & 1023;
    int co = (g >> 10) & 511;
    int b = g >> 19;
    size_t zxi = (size_t)co * 4096 + nxoff + b * 1024 + s;
    float zi = zx[zxi]                       + bias[co];
    float zf = zx[zxi + (size_t)512 * 4096]  + bias[co + 512];
    float zc = zx[zxi + (size_t)1024 * 4096] + bias[co + 1024];
    float zo = zx[zxi + (size_t)1536 * 4096] + bias[co + 1536];
    float Cp = 0.f;
    if (!is_first) {
        size_t zhi = (size_t)co * 2048 + b * 1024 + s;
        zi += zh[zhi];
        zf += zh[zhi + (size_t)512 * 2048];
        zc += zh[zhi + (size_t)1024 * 2048];
        zo += zh[zhi + (size_t)1536 * 2048];
        Cp = C[g];
    }
    int ps = co * 1024 + s;
    float gi = sigmoidf(zi + wci[ps] * Cp);
    float gf = sigmoidf(zf + wcf[ps] * Cp);
    float Cn = gf * Cp + gi * fmaxf(zc, 0.f);
    float go = sigmoidf(zo + wco[ps] * Cn);
    float Hn = go * fmaxf(Cn, 0.f);
    C[g] = Cn;
    Y[((size_t)(b * 512 + co) * T_STEPS + t) * 1024 + s] = f2bf(Hn);
    if (outp) outp[g] = sigmoidf(Hn);
}

// ---------------------------------------------------------------------------
extern "C" void kernel_launch(void* const* d_in, const int* in_sizes, int n_in,
                              void* d_out, int out_size, void* d_ws, size_t ws_size,
                              hipStream_t stream) {
    const float* x = (const float*)d_in[0];

    char* ws = (char*)d_ws;
    size_t off = 0;
    auto carve = [&](size_t bytes) { char* p = ws + off; off += (bytes + 255) & ~(size_t)255; return p; };

    u16*   Wx   = (u16*)  carve((size_t)16 * 144 * 4096 * 2);          // 18.9 MB
    u16*   Wh   = (u16*)  carve((size_t)16 * 144 * 4096 * 2);          // 18.9 MB
    float* Zx   = (float*)carve((size_t)2048 * 4096 * 4);              // 33.6 MB
    float* Zh   = (float*)carve((size_t)2048 * 2048 * 4);              // 16.8 MB
    float* Cbuf = (float*)carve((size_t)2 * 512 * 1024 * 4);           //  4.2 MB
    u16*   Y1   = (u16*)  carve((size_t)2 * 512 * T_STEPS * 1024 * 2); // 16.8 MB
    u16*   Y2   = (u16*)  carve((size_t)2 * 512 * T_STEPS * 1024 * 2); // 16.8 MB
    (void)ws_size; (void)in_sizes; (void)n_in; (void)out_size;         // ~126 MB total

    for (int l = 0; l < 3; ++l) {
        const float* w    = (const float*)d_in[1 + 5 * l];
        const float* bias = (const float*)d_in[2 + 5 * l];
        const float* wci  = (const float*)d_in[3 + 5 * l];
        const float* wcf  = (const float*)d_in[4 + 5 * l];
        const float* wco  = (const float*)d_in[5 + 5 * l];
        const void*  inl  = (l == 0) ? (const void*)x : (l == 1 ? (const void*)Y1 : (const void*)Y2);
        u16* Ycur = (l == 0) ? Y1 : (l == 1 ? Y2 : Y1);

        repack_w<<<9216, 256, 0, stream>>>(w, Wx, Wh);

        for (int t = 0; t < T_STEPS; ++t) {
            if ((t & 1) == 0) {
                // x-part GEMM for timesteps t, t+1: N = 4096
                if (l == 0)
                    conv_gemm<true, true><<<dim3(32, 16), 512, 0, stream>>>(
                        Wx, inl, t, Zx, 4096);
                else
                    conv_gemm<true, false><<<dim3(32, 16), 512, 0, stream>>>(
                        Wx, inl, t, Zx, 4096);
            }
            if (t > 0) {
                // h-part GEMM on this layer's H_{t-1}: N = 2048
                conv_gemm<false, false><<<dim3(16, 16), 512, 0, stream>>>(
                    Wh, Ycur, t - 1, Zh, 2048);
            }
            float* outp = (l == 2 && t == T_STEPS - 1) ? (float*)d_out : nullptr;
            gates_kernel<<<4096, 256, 0, stream>>>(
                Zx, (t & 1) * 2048, Zh, bias, wci, wcf, wco,
                Cbuf, (t == 0) ? 1 : 0, Ycur, t, outp);
        }
    }
}